// Round 3
// baseline (52.842 us; speedup 1.0000x reference)
//
#include <hip/hip_runtime.h>

#define NSEQ 2048   // B*S
#define TT 30       // T
#define DIN 500
#define NLAYER 64

// fast transcendentals: v_exp_f32 / v_rcp_f32 (~1 ulp rel err; threshold is 2% rel)
__device__ __forceinline__ float fexp(float x) {
    return __builtin_amdgcn_exp2f(x * 1.4426950408889634f);
}
__device__ __forceinline__ float fsigmoid(float x) {
    return __builtin_amdgcn_rcpf(1.0f + fexp(-x));
}
__device__ __forceinline__ float ftanh_(float x) {
    return fmaf(-2.0f, __builtin_amdgcn_rcpf(1.0f + fexp(2.0f * x)), 1.0f);
}
__device__ __forceinline__ float rdlane(float v, int l) {
    return __builtin_bit_cast(float, __builtin_amdgcn_readlane(__builtin_bit_cast(int, v), l));
}
// DPP cross-lane (2-cycle VALU, off the LDS pipe)
template <int CTRL>
__device__ __forceinline__ float dppmv(float v) {
    return __builtin_bit_cast(float, __builtin_amdgcn_update_dpp(
        0, __builtin_bit_cast(int, v), CTRL, 0xF, 0xF, false));
}
#define DPP_ROW_SHR1   0x111
#define DPP_ROW_SHR2   0x112
#define DPP_ROW_SHR4   0x114
#define DPP_ROW_SHR8   0x118
#define DPP_BCAST15    0x142
#define DPP_BCAST31    0x143
#define DPP_SHR1       0x138  // wave_shr:1 (lane l <- lane l-1)

// x float4 pairs with chunk-reversed weight float4: component c <-> component 3-c
__device__ __forceinline__ float dot4rev(const float4 xv, const float4 wv, float acc) {
    acc = fmaf(xv.x, wv.w, acc);
    acc = fmaf(xv.y, wv.z, acc);
    acc = fmaf(xv.z, wv.y, acc);
    acc = fmaf(xv.w, wv.x, acc);
    return acc;
}
// 64-lane sum: log-prefix within 16-lane rows, then bcast15/bcast31 stitches
// rows; total lands in lane 63. (old=0, bound_ctrl=false: shifted-in lanes add 0)
__device__ __forceinline__ float red64(float a) {
    a += dppmv<DPP_ROW_SHR1>(a);
    a += dppmv<DPP_ROW_SHR2>(a);
    a += dppmv<DPP_ROW_SHR4>(a);
    a += dppmv<DPP_ROW_SHR8>(a);
    a += dppmv<DPP_BCAST15>(a);
    a += dppmv<DPP_BCAST31>(a);
    return a;   // lane 63 = full 64-lane sum
}

// ---------------- K1: layer-0 GEMV (memory-bound) ----------------
// 64-lane-slice dot: lane l owns x/w quads l and 64+l of each 500-float row
// (weights stored ONCE per wave: 8 float4 = 32 VGPR, vs v3's 4x-redundant 128).
// Wave = (seq, t-octet): 2048 blocks x 4 waves = 8192 waves; launch_bounds
// (256,4) caps VGPR at 128 -> 16 waves/CU resident, grid 2x oversubscribed ->
// waves at decorrelated phases keep the memory pipe full. Loads issue 3
// timesteps ahead (6 in flight, ~6 KB/wave).
__global__ __launch_bounds__(256, 4) void lstm_gemv(
    const float* __restrict__ x,       // (NSEQ, TT*DIN)
    const float* __restrict__ w_ih0,   // (4, DIN)
    float4* __restrict__ preg)         // (NSEQ, TT) raw gate preacts (no bias)
{
    const int tid  = threadIdx.x;
    const int lane = tid & 63;
    const int w    = tid >> 6;
    const int n    = blockIdx.x;

    // reversed weights for quads q=lane (partner 124-lane) and q=64+lane
    // (partner 60-lane); lanes 61-63 have no second quad -> zero weight.
    const float4* __restrict__ w4 = (const float4*)w_ih0;   // 500 quads, row g*125
    const float4 z4 = make_float4(0.f, 0.f, 0.f, 0.f);
    float4 wq0[4], wq1[4];
#pragma unroll
    for (int g = 0; g < 4; ++g) {
        wq0[g] = w4[g * 125 + (124 - lane)];
        wq1[g] = (lane < 61) ? w4[g * 125 + (60 - lane)] : z4;
    }

    const float4* __restrict__ xq = (const float4*)(x + (size_t)n * (TT * DIN));
    const int xb_idx = (lane < 61) ? (64 + lane) : 124;   // clamp: weight is 0

    float4 xa[8], xb[8];            // indexed by unrolled constants only
    auto issue = [&](int i) {
        const int t = 8 * w + i;    // wave-uniform guard
        if (t < TT) {
            const float4* __restrict__ p = xq + (TT - 1 - t) * 125;
            xa[i] = p[lane];
            xb[i] = p[xb_idx];
        }
    };
    issue(0); issue(1); issue(2);
    __builtin_amdgcn_sched_barrier(0);
#pragma unroll
    for (int i = 0; i < 8; ++i) {
        if (i + 3 < 8) issue(i + 3);           // stay 3 t ahead
        __builtin_amdgcn_sched_barrier(0);     // pin issue before compute
        const int t = 8 * w + i;
        if (t < TT) {
            float a0 = dot4rev(xa[i], wq0[0], 0.f); a0 = dot4rev(xb[i], wq1[0], a0);
            float a1 = dot4rev(xa[i], wq0[1], 0.f); a1 = dot4rev(xb[i], wq1[1], a1);
            float a2 = dot4rev(xa[i], wq0[2], 0.f); a2 = dot4rev(xb[i], wq1[2], a2);
            float a3 = dot4rev(xa[i], wq0[3], 0.f); a3 = dot4rev(xb[i], wq1[3], a3);
            a0 = red64(a0); a1 = red64(a1); a2 = red64(a2); a3 = red64(a3);
            if (lane == 63) preg[n * TT + t] = make_float4(a0, a1, a2, a3);
        }
        __builtin_amdgcn_sched_barrier(0);
    }
}

// ---------------- K2: 64-layer recurrence (latency-bound) ----------------
// One wave per sequence, (layer,time) anti-diagonal wavefront, lane = layer.
// Identical math to the proven fused phase-2; pre[] comes from workspace.
__global__ __launch_bounds__(256, 2) void lstm_rec(
    const float4* __restrict__ preg,   // (NSEQ, TT)
    const float* __restrict__ w_hh0,   // (4,1)
    const float* __restrict__ b_ih0,   // (4)
    const float* __restrict__ b_hh0,   // (4)
    const float* __restrict__ w_ih,    // (63,4,1)
    const float* __restrict__ w_hh,    // (63,4,1)
    const float* __restrict__ b_ih,    // (63,4)
    const float* __restrict__ b_hh,    // (63,4)
    float* __restrict__ out)           // (NSEQ, TT)
{
    const int tid  = threadIdx.x;
    const int lane = tid & 63;
    const int w    = tid >> 6;
    const int n    = blockIdx.x * 4 + w;

    // ---- parameters ----
    const int l = (lane == 0) ? 0 : (lane - 1);
    const float4 wihv  = *(const float4*)(w_ih + l * 4);
    const float4 whhv  = *(const float4*)(w_hh + l * 4);
    const float4 bihv  = *(const float4*)(b_ih + l * 4);
    const float4 bhhv  = *(const float4*)(b_hh + l * 4);
    const float4 whh0v = *(const float4*)(w_hh0);
    const float4 bi0v  = *(const float4*)(b_ih0);
    const float4 bh0v  = *(const float4*)(b_hh0);

    float wih0, wih1, wih2, wih3, whh0, whh1, whh2, whh3;
    float bia0, bia1, bia2, bia3;
    if (lane == 0) {
        wih0 = wih1 = wih2 = wih3 = 0.f;
        bia0 = bia1 = bia2 = bia3 = 0.f;
        whh0 = whh0v.x; whh1 = whh0v.y; whh2 = whh0v.z; whh3 = whh0v.w;
    } else {
        wih0 = wihv.x; wih1 = wihv.y; wih2 = wihv.z; wih3 = wihv.w;
        whh0 = whhv.x; whh1 = whhv.y; whh2 = whhv.z; whh3 = whhv.w;
        bia0 = bihv.x + bhhv.x; bia1 = bihv.y + bhhv.y;
        bia2 = bihv.z + bhhv.z; bia3 = bihv.w + bhhv.w;
    }
    float pg0 = 0.f, pg1 = 0.f, pg2 = 0.f, pg3 = 0.f;
    if (lane < TT) {
        const float4 q = preg[n * TT + lane];
        pg0 = q.x + bi0v.x + bh0v.x;
        pg1 = q.y + bi0v.y + bh0v.y;
        pg2 = q.z + bi0v.z + bh0v.z;
        pg3 = q.w + bi0v.w + bh0v.w;
    }

    // ---- (layer,time) wavefront ----
    float h = 0.f, c = 0.f;
    for (int k = 0; k < NLAYER + TT - 1; ++k) {
        const float h_in = dppmv<DPP_SHR1>(h);   // layer l-1's h at this lane's t
        const int t = k - lane;
        const bool active = (t >= 0) && (t < TT);

        float g0, g1, g2, g3;
        if (lane == 0) {
            g0 = g1 = g2 = g3 = 0.f;
        } else {
            g0 = fmaf(h_in, wih0, bia0);
            g1 = fmaf(h_in, wih1, bia1);
            g2 = fmaf(h_in, wih2, bia2);
            g3 = fmaf(h_in, wih3, bia3);
        }
        if (k < TT) {   // uniform: broadcast lane k's pre0 quad via SGPR
            const float p0 = rdlane(pg0, k);
            const float p1 = rdlane(pg1, k);
            const float p2 = rdlane(pg2, k);
            const float p3 = rdlane(pg3, k);
            if (lane == 0) { g0 = p0; g1 = p1; g2 = p2; g3 = p3; }
        }
        g0 = fmaf(h, whh0, g0);
        g1 = fmaf(h, whh1, g1);
        g2 = fmaf(h, whh2, g2);
        g3 = fmaf(h, whh3, g3);

        const float ig = fsigmoid(g0);
        const float fg = fsigmoid(g1);
        const float gg = ftanh_(g2);
        const float og = fsigmoid(g3);
        const float cn = fmaf(fg, c, ig * gg);
        const float hn = og * ftanh_(cn);

        if (active) { c = cn; h = hn; }
        if (lane == 63 && active) out[(size_t)n * TT + t] = hn;
    }
}

extern "C" void kernel_launch(void* const* d_in, const int* in_sizes, int n_in,
                              void* d_out, int out_size, void* d_ws, size_t ws_size,
                              hipStream_t stream) {
    const float* x     = (const float*)d_in[0];
    const float* w_ih0 = (const float*)d_in[1];
    const float* w_hh0 = (const float*)d_in[2];
    const float* b_ih0 = (const float*)d_in[3];
    const float* b_hh0 = (const float*)d_in[4];
    const float* w_ih  = (const float*)d_in[5];
    const float* w_hh  = (const float*)d_in[6];
    const float* b_ih  = (const float*)d_in[7];
    const float* b_hh  = (const float*)d_in[8];
    float* out = (float*)d_out;

    float4* preg = (float4*)d_ws;   // 2048*30*16 B = 983 KB staging

    lstm_gemv<<<NSEQ, 256, 0, stream>>>(x, w_ih0, preg);
    lstm_rec<<<NSEQ / 4, 256, 0, stream>>>(preg, w_hh0, b_ih0, b_hh0,
                                           w_ih, w_hh, b_ih, b_hh, out);
}

// Round 4
// 49.041 us; speedup vs baseline: 1.0775x; 1.0775x over previous
//
#include <hip/hip_runtime.h>

#define NSEQ 2048   // B*S
#define TT 30       // T
#define DIN 500
#define NLAYER 64

#define RING 7                    // LDS ring slots per wave
#define SLOT 2048                 // bytes per slot (2000-B chunk, padded)
#define PREOFF (RING * SLOT)      // pre[] region inside wave's LDS
#define WREG (PREOFF + 512)       // 14848 B per wave

// fast transcendentals: v_exp_f32 / v_rcp_f32 (~1 ulp rel err; threshold is 2% rel)
__device__ __forceinline__ float fexp(float x) {
    return __builtin_amdgcn_exp2f(x * 1.4426950408889634f);
}
__device__ __forceinline__ float fsigmoid(float x) {
    return __builtin_amdgcn_rcpf(1.0f + fexp(-x));
}
__device__ __forceinline__ float ftanh_(float x) {
    return fmaf(-2.0f, __builtin_amdgcn_rcpf(1.0f + fexp(2.0f * x)), 1.0f);
}
__device__ __forceinline__ float rdlane(float v, int l) {
    return __builtin_bit_cast(float, __builtin_amdgcn_readlane(__builtin_bit_cast(int, v), l));
}
template <int CTRL>
__device__ __forceinline__ float dppmv(float v) {
    return __builtin_bit_cast(float, __builtin_amdgcn_update_dpp(
        0, __builtin_bit_cast(int, v), CTRL, 0xF, 0xF, false));
}
#define DPP_ROW_SHR1   0x111
#define DPP_ROW_SHR2   0x112
#define DPP_ROW_SHR4   0x114
#define DPP_ROW_SHR8   0x118
#define DPP_BCAST15    0x142
#define DPP_BCAST31    0x143
#define DPP_SHR1       0x138  // wave_shr:1 (lane l <- lane l-1)

__device__ __forceinline__ float dot4rev(const float4 xv, const float4 wv, float acc) {
    acc = fmaf(xv.x, wv.w, acc);
    acc = fmaf(xv.y, wv.z, acc);
    acc = fmaf(xv.z, wv.y, acc);
    acc = fmaf(xv.w, wv.x, acc);
    return acc;
}
// 64-lane sum; total lands in lane 63 (validated in v4)
__device__ __forceinline__ float red64(float a) {
    a += dppmv<DPP_ROW_SHR1>(a);
    a += dppmv<DPP_ROW_SHR2>(a);
    a += dppmv<DPP_ROW_SHR4>(a);
    a += dppmv<DPP_ROW_SHR8>(a);
    a += dppmv<DPP_BCAST15>(a);
    a += dppmv<DPP_BCAST31>(a);
    return a;
}

// global->LDS direct copy: 16 B/lane, zero VGPR landing cost.
// LDS dest = wave-uniform base + lane*16 (linear); global src is per-lane.
__device__ __forceinline__ void gld16(const void* g, void* l) {
    __builtin_amdgcn_global_load_lds(
        (const __attribute__((address_space(1))) void*)g,
        (__attribute__((address_space(3))) void*)l, 16, 0, 0);
}
template <int N> __device__ __forceinline__ void waitv() {
    asm volatile("s_waitcnt vmcnt(%0)" :: "n"(N) : "memory");
}

// v5: one wave per sequence; x streamed via global_load_lds into a 7-slot
// per-wave LDS ring, 6 chunks (12 KB) in flight with hand-counted vmcnt.
// Rationale: v1-v4 all collapsed to ~1 outstanding load/wave because the
// VGPR allocator destroyed every register-landed prefetch (v3: VGPR=128 =
// exactly the weight array). GLL needs no landing registers, so depth is
// structural. Phase 1 math = v4 K1 slice layout (validated); phase 2 =
// v2 wavefront (validated).
__global__ __launch_bounds__(256, 2) void fused_lstm(
    const float* __restrict__ x,       // (NSEQ, TT*DIN)
    const float* __restrict__ w_ih0,   // (4, DIN)
    const float* __restrict__ w_hh0,   // (4,1)
    const float* __restrict__ b_ih0,   // (4)
    const float* __restrict__ b_hh0,   // (4)
    const float* __restrict__ w_ih,    // (63,4,1)
    const float* __restrict__ w_hh,    // (63,4,1)
    const float* __restrict__ b_ih,    // (63,4)
    const float* __restrict__ b_hh,    // (63,4)
    float* __restrict__ out)           // (NSEQ, TT)
{
    __shared__ __align__(16) char lds[4 * WREG];   // 59392 B < 64 KB static cap

    const int tid  = threadIdx.x;
    const int lane = tid & 63;
    const int w    = tid >> 6;
    const int n    = blockIdx.x * 4 + w;
    char* const  lwb  = lds + w * WREG;
    float* const prew = (float*)(lwb + PREOFF);

    // ---- phase-2 param loads issued first (latency hides under phase 1) ----
    const int l = (lane == 0) ? 0 : (lane - 1);
    const float4 wihv  = *(const float4*)(w_ih + l * 4);
    const float4 whhv  = *(const float4*)(w_hh + l * 4);
    const float4 bihv  = *(const float4*)(b_ih + l * 4);
    const float4 bhhv  = *(const float4*)(b_hh + l * 4);
    const float4 whh0v = *(const float4*)(w_hh0);
    const float4 bi0v  = *(const float4*)(b_ih0);
    const float4 bh0v  = *(const float4*)(b_hh0);
    __builtin_amdgcn_sched_barrier(0);

    // ---- slice weights (v4 layout): lane l pairs x-quads {l, 64+l} of chunk
    // cc with reversed w-quads {124-l, 60-l}; 8 float4 = 32 VGPR ----
    const float4* __restrict__ w4 = (const float4*)w_ih0;
    const float4 z4 = make_float4(0.f, 0.f, 0.f, 0.f);
    float4 wq0[4], wq1[4];
#pragma unroll
    for (int g = 0; g < 4; ++g) {
        wq0[g] = w4[g * 125 + (124 - lane)];
        wq1[g] = (lane < 61) ? w4[g * 125 + (60 - lane)] : z4;
    }
    __builtin_amdgcn_sched_barrier(0);

    // ---- pre-issue chunks t=0..5 (12 GLL, 12 KB in flight) ----
    // consumption index t uses memory chunk (29-t); chunk = 2000 B, 16-aligned
    const float* __restrict__ grow = x + (size_t)n * (TT * DIN);
    {
        const float* gp = grow + 29 * 500;
        int off = 0;
#pragma unroll
        for (int j = 0; j < 6; ++j) {
            gld16(gp + 4 * lane, lwb + off);                 // quads 0..63
            gld16(gp + 244 + 4 * lane, lwb + off + 976);     // quads 61..124
            gp -= 500; off += SLOT;
        }
    }

    const int lmin = (lane < 61) ? lane : 60;   // lanes 61-63: dummy, weight 0

    auto consume = [&](int t, int offc) {
        const float4 xa = *(const float4*)(lwb + offc + 16 * lane);
        const float4 xb = *(const float4*)(lwb + offc + 1024 + 16 * lmin);
        float a0 = dot4rev(xa, wq0[0], 0.f); a0 = dot4rev(xb, wq1[0], a0);
        float a1 = dot4rev(xa, wq0[1], 0.f); a1 = dot4rev(xb, wq1[1], a1);
        float a2 = dot4rev(xa, wq0[2], 0.f); a2 = dot4rev(xb, wq1[2], a2);
        float a3 = dot4rev(xa, wq0[3], 0.f); a3 = dot4rev(xb, wq1[3], a3);
        a0 = red64(a0); a1 = red64(a1); a2 = red64(a2); a3 = red64(a3);
        if (lane == 63) *(float4*)(prew + 4 * t) = make_float4(a0, a1, a2, a3);
    };

    // ---- main loop: steady state 12 GLL outstanding, wait for oldest 2 ----
    // N = issued_after_chunk_t = 2*(t+6 - t) - 2 = 10 for t<=24 (in-order vmcnt
    // retirement makes this invariant to the param/weight loads above).
    int offc = 0, offi = 6 * SLOT;
    const float* gp = grow + 23 * 500;          // memory chunk for t=6
    for (int t = 0; t < 24; ++t) {
        waitv<10>();
        consume(t, offc);
        offc += SLOT; if (offc == RING * SLOT) offc = 0;
        // slot being refilled = slot consumed at t-1; lgkm in-order + this
        // wait guarantees its ds_reads retired before the GLL write lands.
        asm volatile("s_waitcnt lgkmcnt(3)" ::: "memory");
        gld16(gp + 4 * lane, lwb + offi);
        gld16(gp + 244 + 4 * lane, lwb + offi + 976);
        gp -= 500;
        offi += SLOT; if (offi == RING * SLOT) offi = 0;
    }
    // tail: no more issues; drain 10,8,6,4,2,0
    waitv<10>(); consume(24, offc); offc += SLOT; if (offc == RING * SLOT) offc = 0;
    waitv<8>();  consume(25, offc); offc += SLOT; if (offc == RING * SLOT) offc = 0;
    waitv<6>();  consume(26, offc); offc += SLOT; if (offc == RING * SLOT) offc = 0;
    waitv<4>();  consume(27, offc); offc += SLOT; if (offc == RING * SLOT) offc = 0;
    waitv<2>();  consume(28, offc); offc += SLOT; if (offc == RING * SLOT) offc = 0;
    waitv<0>();  consume(29, offc);

    asm volatile("s_waitcnt lgkmcnt(0)" ::: "memory");   // pre[] visible

    // ---- phase-2 parameters ----
    float wih0, wih1, wih2, wih3, whh0, whh1, whh2, whh3;
    float bia0, bia1, bia2, bia3;
    if (lane == 0) {
        wih0 = wih1 = wih2 = wih3 = 0.f;
        bia0 = bia1 = bia2 = bia3 = 0.f;
        whh0 = whh0v.x; whh1 = whh0v.y; whh2 = whh0v.z; whh3 = whh0v.w;
    } else {
        wih0 = wihv.x; wih1 = wihv.y; wih2 = wihv.z; wih3 = wihv.w;
        whh0 = whhv.x; whh1 = whhv.y; whh2 = whhv.z; whh3 = whhv.w;
        bia0 = bihv.x + bhhv.x; bia1 = bihv.y + bhhv.y;
        bia2 = bihv.z + bhhv.z; bia3 = bihv.w + bhhv.w;
    }
    float pg0 = 0.f, pg1 = 0.f, pg2 = 0.f, pg3 = 0.f;
    if (lane < TT) {
        const float4 q = *(const float4*)&prew[lane * 4];
        pg0 = q.x + bi0v.x + bh0v.x;
        pg1 = q.y + bi0v.y + bh0v.y;
        pg2 = q.z + bi0v.z + bh0v.z;
        pg3 = q.w + bi0v.w + bh0v.w;
    }

    // ---- phase 2: (layer,time) wavefront, lane = layer (validated v2/v4) ----
    float h = 0.f, c = 0.f;
    for (int k = 0; k < NLAYER + TT - 1; ++k) {
        const float h_in = dppmv<DPP_SHR1>(h);
        const int t = k - lane;
        const bool active = (t >= 0) && (t < TT);

        float g0, g1, g2, g3;
        if (lane == 0) {
            g0 = g1 = g2 = g3 = 0.f;
        } else {
            g0 = fmaf(h_in, wih0, bia0);
            g1 = fmaf(h_in, wih1, bia1);
            g2 = fmaf(h_in, wih2, bia2);
            g3 = fmaf(h_in, wih3, bia3);
        }
        if (k < TT) {
            const float p0 = rdlane(pg0, k);
            const float p1 = rdlane(pg1, k);
            const float p2 = rdlane(pg2, k);
            const float p3 = rdlane(pg3, k);
            if (lane == 0) { g0 = p0; g1 = p1; g2 = p2; g3 = p3; }
        }
        g0 = fmaf(h, whh0, g0);
        g1 = fmaf(h, whh1, g1);
        g2 = fmaf(h, whh2, g2);
        g3 = fmaf(h, whh3, g3);

        const float ig = fsigmoid(g0);
        const float fg = fsigmoid(g1);
        const float gg = ftanh_(g2);
        const float og = fsigmoid(g3);
        const float cn = fmaf(fg, c, ig * gg);
        const float hn = og * ftanh_(cn);

        if (active) { c = cn; h = hn; }
        if (lane == 63 && active) out[(size_t)n * TT + t] = hn;
    }
}

extern "C" void kernel_launch(void* const* d_in, const int* in_sizes, int n_in,
                              void* d_out, int out_size, void* d_ws, size_t ws_size,
                              hipStream_t stream) {
    const float* x     = (const float*)d_in[0];
    const float* w_ih0 = (const float*)d_in[1];
    const float* w_hh0 = (const float*)d_in[2];
    const float* b_ih0 = (const float*)d_in[3];
    const float* b_hh0 = (const float*)d_in[4];
    const float* w_ih  = (const float*)d_in[5];
    const float* w_hh  = (const float*)d_in[6];
    const float* b_ih  = (const float*)d_in[7];
    const float* b_hh  = (const float*)d_in[8];
    float* out = (float*)d_out;

    fused_lstm<<<NSEQ / 4, 256, 0, stream>>>(x, w_ih0, w_hh0, b_ih0, b_hh0,
                                             w_ih, w_hh, b_ih, b_hh, out);
}